// Round 4
// baseline (242.092 us; speedup 1.0000x reference)
//
#include <hip/hip_runtime.h>

// Problem constants (from reference setup_inputs)
#define BATCH 16
#define CIN   3
#define H     384
#define W     384
#define HO    382
#define WO    382
#define WO2   191   // WO/2 pixel-pairs per row (exact: 382 = 2*191)
#define OFFC  18    // offset channels = 2*K
#define OOUT  3     // dcn output channels
#define KTAPS 9

typedef float vfloat2 __attribute__((ext_vector_type(2)));  // native vec for nontemporal builtins

// Per-pixel deformable gather + 3ch dot, accumulating into a0/a1/a2.
__device__ __forceinline__ void gather_px(const float* __restrict__ xb,
                                          const float* __restrict__ off,
                                          int ho, int wo,
                                          const float* __restrict__ s_dw,
                                          float& a0, float& a1, float& a2)
{
    #pragma unroll
    for (int k = 0; k < KTAPS; ++k) {
        const int ky = k / 3;
        const int kx = k % 3;
        const float py = off[2 * k]     + (float)(ho + ky);
        const float px = off[2 * k + 1] + (float)(wo + kx);
        const float y0f = floorf(py);
        const float x0f = floorf(px);
        const float wy = py - y0f;
        const float wx = px - x0f;
        const int y0 = (int)y0f;
        const int x0 = (int)x0f;
        const int y1 = y0 + 1;
        const int x1 = x0 + 1;

        const bool vy0 = (y0 >= 0) && (y0 < H);
        const bool vy1 = (y1 >= 0) && (y1 < H);
        const bool vx0 = (x0 >= 0) && (x0 < W);
        const bool vx1 = (x1 >= 0) && (x1 < W);

        const int cy0 = min(max(y0, 0), H - 1);
        const int cy1 = min(max(y1, 0), H - 1);
        const int cx0 = min(max(x0, 0), W - 1);
        const int cx1 = min(max(x1, 0), W - 1);

        const float w00 = (vy0 && vx0) ? (1.f - wy) * (1.f - wx) : 0.f;
        const float w01 = (vy0 && vx1) ? (1.f - wy) * wx         : 0.f;
        const float w10 = (vy1 && vx0) ? wy * (1.f - wx)         : 0.f;
        const float w11 = (vy1 && vx1) ? wy * wx                 : 0.f;

        const int i00 = cy0 * W + cx0;
        const int i01 = cy0 * W + cx1;
        const int i10 = cy1 * W + cx0;
        const int i11 = cy1 * W + cx1;

        #pragma unroll
        for (int c = 0; c < CIN; ++c) {
            const float* xc = xb + c * (H * W);
            float s = xc[i00] * w00;
            s = fmaf(xc[i01], w01, s);
            s = fmaf(xc[i10], w10, s);
            s = fmaf(xc[i11], w11, s);
            a0 = fmaf(s_dw[0 * 27 + c * 9 + k], s, a0);
            a1 = fmaf(s_dw[1 * 27 + c * 9 + k], s, a1);
            a2 = fmaf(s_dw[2 * 27 + c * 9 + k], s, a2);
        }
    }
}

__global__ __launch_bounds__(256)
void deform_fused2_kernel(const float* __restrict__ x,
                          const float* __restrict__ conv_w,
                          const float* __restrict__ conv_b,
                          const float* __restrict__ dcn_w,
                          const float* __restrict__ dcn_b,
                          float* __restrict__ out)
{
    // Stage all weights in LDS (588 floats). OFFC*27=486 > 256 threads ->
    // grid-stride staging (round-1 bug).
    __shared__ float s_cw[OFFC * 27];
    __shared__ float s_cb[OFFC];
    __shared__ float s_dw[OOUT * 27];
    __shared__ float s_db[OOUT];

    const int t = threadIdx.x;
    for (int i = t; i < OFFC * 27; i += 256) s_cw[i] = conv_w[i];
    if (t < OFFC)      s_cb[t] = conv_b[t];
    if (t < OOUT * 27) s_dw[t] = dcn_w[t];
    if (t < OOUT)      s_db[t] = dcn_b[t];
    __syncthreads();

    const int total = BATCH * HO * WO2;   // one thread = 2 adjacent pixels
    const int gid = blockIdx.x * 256 + t;
    if (gid >= total) return;

    const int g   = gid % WO2;
    const int tmp = gid / WO2;
    const int ho  = tmp % HO;
    const int b   = tmp / HO;
    const int wo  = 2 * g;                // even -> 8B-aligned float2 loads

    const float* xb = x + b * (CIN * H * W);

    // Patch rows ho..ho+2, cols wo..wo+3, as float2 pairs (always in-bounds:
    // wo<=380 -> cols<=383; ho<=381 -> rows<=383).
    float xp[CIN][3][4];
    #pragma unroll
    for (int c = 0; c < CIN; ++c) {
        #pragma unroll
        for (int i = 0; i < 3; ++i) {
            const vfloat2* p = (const vfloat2*)(xb + c * (H * W) + (ho + i) * W + wo);
            const vfloat2 lo = p[0];
            const vfloat2 hi = p[1];
            xp[c][i][0] = lo.x; xp[c][i][1] = lo.y;
            xp[c][i][2] = hi.x; xp[c][i][3] = hi.y;
        }
    }

    // Offset conv for both pixels, sharing each LDS weight read.
    float off0[OFFC], off1[OFFC];
    #pragma unroll
    for (int o = 0; o < OFFC; ++o) {
        float a0 = s_cb[o];
        float a1 = a0;
        const float* wv = &s_cw[o * 27];
        #pragma unroll
        for (int c = 0; c < CIN; ++c)
            #pragma unroll
            for (int i = 0; i < 3; ++i)
                #pragma unroll
                for (int j = 0; j < 3; ++j) {
                    const float wij = wv[c * 9 + i * 3 + j];
                    a0 = fmaf(wij, xp[c][i][j],     a0);
                    a1 = fmaf(wij, xp[c][i][j + 1], a1);
                }
        off0[o] = a0;
        off1[o] = a1;
    }

    float p0a0 = s_db[0], p0a1 = s_db[1], p0a2 = s_db[2];
    float p1a0 = s_db[0], p1a1 = s_db[1], p1a2 = s_db[2];

    gather_px(xb, off0, ho, wo,     s_dw, p0a0, p0a1, p0a2);
    gather_px(xb, off1, ho, wo + 1, s_dw, p1a0, p1a1, p1a2);

    // Coalesced float2 stores, nontemporal (write-once; keep x in L2).
    const int obase = b * (OOUT * HO * WO) + ho * WO + wo;
    vfloat2* o0 = (vfloat2*)(out + obase);
    vfloat2* o1 = (vfloat2*)(out + obase + HO * WO);
    vfloat2* o2 = (vfloat2*)(out + obase + 2 * HO * WO);
    vfloat2 v0; v0.x = p0a0; v0.y = p1a0;
    vfloat2 v1; v1.x = p0a1; v1.y = p1a1;
    vfloat2 v2; v2.x = p0a2; v2.y = p1a2;
    __builtin_nontemporal_store(v0, o0);
    __builtin_nontemporal_store(v1, o1);
    __builtin_nontemporal_store(v2, o2);
}

extern "C" void kernel_launch(void* const* d_in, const int* in_sizes, int n_in,
                              void* d_out, int out_size, void* d_ws, size_t ws_size,
                              hipStream_t stream) {
    const float* x      = (const float*)d_in[0];
    const float* conv_w = (const float*)d_in[1];
    const float* conv_b = (const float*)d_in[2];
    const float* dcn_w  = (const float*)d_in[3];
    const float* dcn_b  = (const float*)d_in[4];
    float* out = (float*)d_out;

    const int total = BATCH * HO * WO2;
    const int blocks = (total + 255) / 256;
    deform_fused2_kernel<<<blocks, 256, 0, stream>>>(x, conv_w, conv_b, dcn_w, dcn_b, out);
}